// Round 15
// baseline (219.018 us; speedup 1.0000x reference)
//
#include <hip/hip_runtime.h>
#include <math.h>

typedef unsigned short u16;
typedef __attribute__((ext_vector_type(8))) short short8;
typedef __attribute__((ext_vector_type(8))) __bf16 bf16x8;
typedef __attribute__((ext_vector_type(4))) float floatx4;
typedef __attribute__((ext_vector_type(16))) float floatx16;
typedef __attribute__((ext_vector_type(4))) unsigned short u16x4;
typedef __attribute__((ext_vector_type(4))) float float4v;
typedef __attribute__((ext_vector_type(4))) unsigned int uint4v;

static __device__ __forceinline__ float b2f(u16 u) {
  unsigned int x = ((unsigned int)u) << 16;
  return __builtin_bit_cast(float, x);
}
static __device__ __forceinline__ u16 f2b(float f) {
  unsigned int x = __builtin_bit_cast(unsigned int, f);
  x += 0x7fffu + ((x >> 16) & 1u);
  return (u16)(x >> 16);
}
// pack two f32 -> two bf16 in one instruction (T12; no builtin on gfx950)
static __device__ __forceinline__ unsigned int pk2(float lo, float hi) {
  unsigned int r;
  asm("v_cvt_pk_bf16_f32 %0, %1, %2" : "=v"(r) : "v"(lo), "v"(hi));
  return r;
}
static __device__ __forceinline__ float max3f(float a, float b, float c) {
  return fmaxf(fmaxf(a, b), c);  // clang fuses to v_max3_f32
}
static __device__ __forceinline__ void gload_lds16(const void* g, void* l) {
  __builtin_amdgcn_global_load_lds(
      (const __attribute__((address_space(1))) unsigned int*)g,
      (__attribute__((address_space(3))) unsigned int*)l, 16, 0, 0);
}

// ---------- fused fp32 -> bf16 convert for all 5 inputs + RoPE tables ----------
__global__ __launch_bounds__(256) void cvt5_kernel(
    const float* __restrict__ x, const float* __restrict__ wq,
    const float* __restrict__ wk, const float* __restrict__ wv,
    const float* __restrict__ wo, u16* __restrict__ xb, u16* __restrict__ wqb,
    u16* __restrict__ wkb, u16* __restrict__ wvb, u16* __restrict__ wob,
    float* __restrict__ ct, float* __restrict__ st) {
  int bid = blockIdx.x;
  if (bid >= 18432) {  // RoPE cos/sin tables: [S=2048][64] fp32
    int idx = (bid - 18432) * 256 + threadIdx.x;
    int s = idx >> 6, j = idx & 63;
    float inv = powf(10000.0f, -(float)j * (1.0f / 64.0f));
    float ang = (float)s * inv;
    ct[idx] = cosf(ang);
    st[idx] = sinf(ang);
    return;
  }
  const float* in;
  u16* out;
  int i0;
  if (bid < 8192) { in = x; out = xb; i0 = bid; }
  else if (bid < 12288) { in = wq; out = wqb; i0 = bid - 8192; }
  else if (bid < 13312) { in = wk; out = wkb; i0 = bid - 12288; }
  else if (bid < 14336) { in = wv; out = wvb; i0 = bid - 13312; }
  else { in = wo; out = wob; i0 = bid - 14336; }
  int i = i0 * 256 + threadIdx.x;
  float4v v = reinterpret_cast<const float4v*>(in)[i];
  u16x4 o;
  o[0] = f2b(v[0]); o[1] = f2b(v[1]); o[2] = f2b(v[2]); o[3] = f2b(v[3]);
  reinterpret_cast<u16x4*>(out)[i] = o;
}

// ---------- fused K-RoPE + V-transpose (one launch) ----------
__global__ __launch_bounds__(256) void kvprep_kernel(const u16* __restrict__ in,
                                                     u16* __restrict__ kr,
                                                     u16* __restrict__ vtb,
                                                     const float* __restrict__ ct,
                                                     const float* __restrict__ st) {
  __shared__ u16 t[128][66];
  if (blockIdx.x < 512) {
    int idx = blockIdx.x * 256 + threadIdx.x;  // B*S*4*8 = 131072
    int jc = idx & 7;
    int rest = idx >> 3;
    int h = rest & 3;
    int bs = rest >> 2;
    int s = bs & 2047;
    int b = bs >> 11;
    int j0 = jc * 8;
    size_t inoff = (size_t)bs * 3072 + 2048 + h * 128 + j0;
    short8 lo = *reinterpret_cast<const short8*>(&in[inoff]);
    short8 hi = *reinterpret_cast<const short8*>(&in[inoff + 64]);
    short8 o0, o1;
#pragma unroll
    for (int e = 0; e < 8; ++e) {
      float c = ct[s * 64 + j0 + e], sn = st[s * 64 + j0 + e];
      float t1 = b2f((u16)lo[e]);
      float t2 = b2f((u16)hi[e]);
      o0[e] = (short)f2b(t1 * c - t2 * sn);
      o1[e] = (short)f2b(t2 * c + t1 * sn);
    }
    size_t ooff = ((size_t)(b * 4 + h) * 2048 + s) * 128 + j0;
    *reinterpret_cast<short8*>(&kr[ooff]) = o0;
    *reinterpret_cast<short8*>(&kr[ooff + 64]) = o1;
  } else {
    int vb = blockIdx.x - 512;  // 256 blocks
    int s0 = (vb & 31) * 64;
    int by = vb >> 5;
    int b = by >> 2, kv = by & 3;
    int tid = threadIdx.x;
#pragma unroll
    for (int it = 0; it < 32; ++it) {
      int idx = it * 256 + tid;
      int sl = idx >> 7, d = idx & 127;
      t[d][sl] = in[(size_t)(b * 2048 + s0 + sl) * 3072 + 2560 + kv * 128 + d];
    }
    __syncthreads();
#pragma unroll
    for (int it = 0; it < 32; ++it) {
      int idx = it * 256 + tid;
      int d = idx >> 6, sl = idx & 63;
      vtb[(size_t)((b * 4 + kv) * 128 + d) * 2048 + s0 + sl] = t[d][sl];
    }
  }
}

// ---------- bf16 GEMM: triple-buffered LDS + counted vmcnt + raw s_barrier ----------
// C[M][N] = A[M][K] * B[N][K]^T, tile 128xBN (BN = 128 or 64), BK=32, 4 waves.
// Wave (wr, wc) owns output sub-tile rows wr*64..+64, cols wc*(BN/2)..+(BN/2).
// BN=128: 4 loads/stage, vmcnt(4); 48KB LDS, 3 blocks/CU cap.
// BN=64: 3 loads/stage, vmcnt(3); 36KB LDS, 4 blocks/CU -> 2x resident blocks
// for small-N grids (out-proj), hiding the staging chain across blocks.
static __device__ __forceinline__ void store_out(u16* p, float v) { *p = f2b(v); }
static __device__ __forceinline__ void store_out(float* p, float v) { *p = v; }

template <typename OutT, int BN>
__global__ __launch_bounds__(256) void gemm_bt(const u16* __restrict__ A,
                                               const u16* __restrict__ B,
                                               OutT* __restrict__ C, int M, int N, int K) {
  __shared__ __align__(16) u16 Al[3][128 * 32];
  __shared__ __align__(16) u16 Bl[3][BN * 32];
  const int tid = threadIdx.x;
  const int lane = tid & 63;
  const int w = tid >> 6;
  const int wr = w >> 1, wc = w & 1;
  const int lr = lane & 15, lg = lane >> 4;
  const int brow = blockIdx.y, bcol = blockIdx.x;
  const int r0 = lane >> 2, kp = lane & 3;
  constexpr int NFR = BN / 32;  // B frags per wave (4 for 128, 2 for 64)
  const u16* Ag = A + (size_t)(brow * 128) * K;
  const u16* Bg = B + (size_t)(bcol * BN) * K;
  floatx4 acc[4][NFR] = {};
  const int NT = K >> 5;

  auto stage = [&](int buf, int t) {
#pragma unroll
    for (int j = 0; j < 2; ++j) {
      int c = w * 2 + j;
      int row = c * 16 + r0;
      gload_lds16(Ag + (size_t)row * K + t * 32 + kp * 8, &Al[buf][c * 512]);
    }
    if constexpr (BN == 128) {
#pragma unroll
      for (int j = 0; j < 2; ++j) {
        int c = w * 2 + j;
        int row = c * 16 + r0;
        gload_lds16(Bg + (size_t)row * K + t * 32 + kp * 8, &Bl[buf][c * 512]);
      }
    } else {
      int row = w * 16 + r0;
      gload_lds16(Bg + (size_t)row * K + t * 32 + kp * 8, &Bl[buf][w * 512]);
    }
  };

  stage(0, 0);
  stage(1, 1);
  if constexpr (BN == 128)
    asm volatile("s_waitcnt vmcnt(4)\n\ts_barrier" ::: "memory");
  else
    asm volatile("s_waitcnt vmcnt(3)\n\ts_barrier" ::: "memory");

  int cur = 0, nxt = 2;  // nxt = (cur+2)%3
  for (int t = 0; t < NT; ++t) {
    if (t + 2 < NT) stage(nxt, t + 2);
    bf16x8 af[4], bfr[NFR];
#pragma unroll
    for (int m = 0; m < 4; ++m)
      af[m] = *reinterpret_cast<const bf16x8*>(&Al[cur][(wr * 64 + m * 16 + lr) * 32 + lg * 8]);
#pragma unroll
    for (int n = 0; n < NFR; ++n)
      bfr[n] = *reinterpret_cast<const bf16x8*>(
          &Bl[cur][(wc * (BN / 2) + n * 16 + lr) * 32 + lg * 8]);
    __builtin_amdgcn_s_setprio(1);
#pragma unroll
    for (int m = 0; m < 4; ++m)
#pragma unroll
      for (int n = 0; n < NFR; ++n)
        acc[m][n] = __builtin_amdgcn_mfma_f32_16x16x32_bf16(af[m], bfr[n], acc[m][n], 0, 0, 0);
    __builtin_amdgcn_s_setprio(0);
    if (t + 2 < NT) {
      if constexpr (BN == 128)
        asm volatile("s_waitcnt vmcnt(4)\n\ts_barrier" ::: "memory");
      else
        asm volatile("s_waitcnt vmcnt(3)\n\ts_barrier" ::: "memory");
    } else if (t + 1 < NT) {
      asm volatile("s_waitcnt vmcnt(0)\n\ts_barrier" ::: "memory");
    }
    cur = (cur == 2) ? 0 : cur + 1;
    nxt = (nxt == 2) ? 0 : nxt + 1;
  }
#pragma unroll
  for (int m = 0; m < 4; ++m) {
    int row = brow * 128 + wr * 64 + m * 16 + lg * 4;
#pragma unroll
    for (int n = 0; n < NFR; ++n) {
      int col = bcol * BN + wc * (BN / 2) + n * 16 + lr;
#pragma unroll
      for (int i = 0; i < 4; ++i) store_out(&C[(size_t)(row + i) * N + col], acc[m][n][i]);
    }
  }
}

// ---------- causal GQA flash attention (r11 known-good config) ----------
// Uniform 17-tile blocks + combine; double-buffered K/V (64KB, 2 blocks/CU);
// scale folded into Q, ones-trick row-sums, max3 tree, defer-max, cvt_pk+permlane.
// Register floor ~208 total/lane -> 2 blocks/CU hard floor (r10: 4/CU spills).
// Deferred-PV pipeline (r12) measured -3%: per-iter barrier phase-aligns waves,
// so intra-wave ILP restructuring is null. Latency-bound local optimum.
__global__ __launch_bounds__(256, 2) void attn_kernel(
    const u16* __restrict__ QKV, const u16* __restrict__ K,
    const u16* __restrict__ V, const float* __restrict__ ct,
    const float* __restrict__ st, u16* __restrict__ O, u16* __restrict__ Opart,
    float* __restrict__ Mpart, float* __restrict__ Lpart) {
  __shared__ __align__(16) u16 Kl[2][64 * 128];  // [64 k][128 d], slot-XOR swizzled
  __shared__ __align__(16) u16 Vl[2][128 * 64];  // [128 d][64 k], slot-XOR swizzled
  const int tid = threadIdx.x, lane = tid & 63, w = tid >> 6;
  const int ql = lane & 31, h2 = lane >> 5;
  const int idx = blockIdx.x;  // 512 blocks
  const int bh = idx & 31, pp = (idx >> 5) & 7, half = idx >> 8;
  const int b = bh >> 4, hh = bh & 15, kv = hh >> 2;
  const int t_l = 15 - pp, t_s = pp;
  const int pidx = bh * 8 + pp;
  const u16* Kp = K + (size_t)(b * 4 + kv) * 2048 * 128;
  const u16* Vp = V + (size_t)(b * 4 + kv) * 128 * 2048;
  const float cl = 0.08838834764831845f * 1.44269504088896f;  // 1/sqrt(128)*log2e
  const uint4v ones_u = {0x3F803F80u, 0x3F803F80u, 0x3F803F80u, 0x3F803F80u};
  const bf16x8 ones = __builtin_bit_cast(bf16x8, ones_u);

  auto stage = [&](int buf, int kb) {
#pragma unroll
    for (int j = 0; j < 4; ++j) {
      int slot = j * 256 + tid;  // 16B slots
      int row = slot >> 4, d16 = slot & 15;
      gload_lds16(Kp + (size_t)(kb * 64 + row) * 128 + (d16 ^ (row & 15)) * 8,
                  &Kl[buf][(j * 256 + w * 64) * 8]);
      int d = slot >> 3, k8 = slot & 7;
      gload_lds16(Vp + (size_t)d * 2048 + kb * 64 + (k8 ^ (d & 7)) * 8,
                  &Vl[buf][(j * 256 + w * 64) * 8]);
    }
  };

  // run one q-tile over kv tiles [kvs, kve). part: -1 = final write, 0/1 = partial.
  auto run_segment = [&](int t, int kvs, int kve, int part) {
    const int q0w = t * 128 + w * 32;
    const int qg = q0w + ql;
    // Q load + fused RoPE (pre-scaled by cl) -> B-operand frags
    bf16x8 qa[8];
    {
      const u16* qp = QKV + ((size_t)(b * 2048 + qg)) * 3072 + hh * 128;
      short8 rr[8];
#pragma unroll
      for (int dk = 0; dk < 8; ++dk)
        rr[dk] = *reinterpret_cast<const short8*>(qp + dk * 16 + h2 * 8);
      const float* cb = ct + (size_t)qg * 64;
      const float* sb = st + (size_t)qg * 64;
#pragma unroll
      for (int dk = 0; dk < 4; ++dk) {
        short8 olo, ohi;
#pragma unroll
        for (int e = 0; e < 8; ++e) {
          int j = dk * 16 + h2 * 8 + e;  // 0..63
          float c = cb[j] * cl, sn = sb[j] * cl;
          float t1 = b2f((u16)rr[dk][e]);
          float t2 = b2f((u16)rr[dk + 4][e]);
          olo[e] = (short)f2b(t1 * c - t2 * sn);
          ohi[e] = (short)f2b(t2 * c + t1 * sn);
        }
        qa[dk] = __builtin_bit_cast(bf16x8, olo);
        qa[dk + 4] = __builtin_bit_cast(bf16x8, ohi);
      }
    }
    float m_r = -1e30f;
    floatx16 oacc[4] = {};
    floatx16 lsum = {};
    stage(0, kvs);
    __syncthreads();
    int cur = 0;
    for (int kb = kvs; kb < kve; ++kb) {
      if (kb + 1 < kve) stage(cur ^ 1, kb + 1);
      if (kb * 64 <= q0w + 31) {
        const u16* Klc = Kl[cur];
        const u16* Vlc = Vl[cur];
        floatx16 sT0 = {}, sT1 = {};
        __builtin_amdgcn_s_setprio(1);
#pragma unroll
        for (int dk = 0; dk < 8; ++dk) {
          int row0 = ql, row1 = 32 + ql;
          bf16x8 ak0 = *reinterpret_cast<const bf16x8*>(
              &Klc[row0 * 128 + (((dk * 2 + h2) ^ (row0 & 15))) * 8]);
          bf16x8 ak1 = *reinterpret_cast<const bf16x8*>(
              &Klc[row1 * 128 + (((dk * 2 + h2) ^ (row1 & 15))) * 8]);
          sT0 = __builtin_amdgcn_mfma_f32_32x32x16_bf16(ak0, qa[dk], sT0, 0, 0, 0);
          sT1 = __builtin_amdgcn_mfma_f32_32x32x16_bf16(ak1, qa[dk], sT1, 0, 0, 0);
        }
        __builtin_amdgcn_s_setprio(0);
        float x[32];
        const bool domask = (kb * 64 + 63 > q0w);
#pragma unroll
        for (int rg = 0; rg < 16; ++rg) {
          int kloc0 = (rg & 3) + 8 * (rg >> 2) + 4 * h2;
          float v0 = sT0[rg];
          float v1 = sT1[rg];
          if (domask) {
            if (kb * 64 + kloc0 > qg) v0 = -1e30f;
            if (kb * 64 + 32 + kloc0 > qg) v1 = -1e30f;
          }
          x[rg] = v0;
          x[16 + rg] = v1;
        }
        // max tree: 16 pairwise + max3 levels (24 ops)
        float mx[16];
#pragma unroll
        for (int i = 0; i < 16; ++i) mx[i] = fmaxf(x[i], x[i + 16]);
        float y0 = max3f(mx[0], mx[1], mx[2]);
        float y1 = max3f(mx[3], mx[4], mx[5]);
        float y2 = max3f(mx[6], mx[7], mx[8]);
        float y3 = max3f(mx[9], mx[10], mx[11]);
        float y4 = max3f(mx[12], mx[13], mx[14]);
        float tmax = fmaxf(max3f(y0, y1, y2), max3f(y3, y4, mx[15]));
        tmax = fmaxf(tmax, __shfl_xor(tmax, 32));
        if (!__all(tmax - m_r <= 11.0f)) {  // defer-max, log2 units
          float mn = fmaxf(m_r, tmax);
          float al = exp2f(m_r - mn);
          m_r = mn;
#pragma unroll
          for (int rg = 0; rg < 16; ++rg) {
            int rowq = (rg & 3) + 8 * (rg >> 2) + 4 * h2;
            float arow = __shfl(al, rowq);
            oacc[0][rg] *= arow; oacc[1][rg] *= arow;
            oacc[2][rg] *= arow; oacc[3][rg] *= arow;
            lsum[rg] *= arow;
          }
        }
        float p[32];
#pragma unroll
        for (int i = 0; i < 32; ++i) p[i] = exp2f(x[i] - m_r);
        bf16x8 pa[4];
#pragma unroll
        for (int ka = 0; ka < 2; ++ka) {
          const int o = ka * 16;
          unsigned int x0 = pk2(p[o + 0], p[o + 1]);
          unsigned int x1 = pk2(p[o + 2], p[o + 3]);
          unsigned int y0u = pk2(p[o + 4], p[o + 5]);
          unsigned int y1u = pk2(p[o + 6], p[o + 7]);
          asm volatile("v_permlane32_swap_b32 %0, %1" : "+v"(x0), "+v"(y0u));
          asm volatile("v_permlane32_swap_b32 %0, %1" : "+v"(x1), "+v"(y1u));
          uint4v f0 = {x0, x1, y0u, y1u};
          pa[ka * 2] = __builtin_bit_cast(bf16x8, f0);
          unsigned int z0 = pk2(p[o + 8], p[o + 9]);
          unsigned int z1 = pk2(p[o + 10], p[o + 11]);
          unsigned int u0 = pk2(p[o + 12], p[o + 13]);
          unsigned int u1 = pk2(p[o + 14], p[o + 15]);
          asm volatile("v_permlane32_swap_b32 %0, %1" : "+v"(z0), "+v"(u0));
          asm volatile("v_permlane32_swap_b32 %0, %1" : "+v"(z1), "+v"(u1));
          uint4v f1 = {z0, z1, u0, u1};
          pa[ka * 2 + 1] = __builtin_bit_cast(bf16x8, f1);
        }
        __builtin_amdgcn_s_setprio(1);
#pragma unroll
        for (int tb = 0; tb < 4; ++tb) {
          int d = tb * 32 + ql;
#pragma unroll
          for (int ks = 0; ks < 4; ++ks) {
            bf16x8 bv = *reinterpret_cast<const bf16x8*>(
                &Vlc[d * 64 + (((ks * 2 + h2) ^ (d & 7))) * 8]);
            oacc[tb] = __builtin_amdgcn_mfma_f32_32x32x16_bf16(pa[ks], bv, oacc[tb], 0, 0, 0);
          }
        }
        // l row-sums via ones-trick: lsum[rg] = sum_k P[rowq][k] for every col
#pragma unroll
        for (int ks = 0; ks < 4; ++ks)
          lsum = __builtin_amdgcn_mfma_f32_32x32x16_bf16(pa[ks], ones, lsum, 0, 0, 0);
        __builtin_amdgcn_s_setprio(0);
      }
      __syncthreads();
      cur ^= 1;
    }
    if (part < 0) {
#pragma unroll
      for (int rg = 0; rg < 16; ++rg) {
        int rowq = (rg & 3) + 8 * (rg >> 2) + 4 * h2;
        float inv = 1.0f / lsum[rg];
        int qrow = t * 128 + w * 32 + rowq;
        size_t base = ((size_t)(b * 2048 + qrow)) * 2048 + hh * 128 + ql;
#pragma unroll
        for (int tb = 0; tb < 4; ++tb)
          O[base + tb * 32] = f2b(oacc[tb][rg] * inv);
      }
    } else {
      // unnormalized partial + (m, l) per q-row
      size_t pb = ((size_t)(part * 256 + pidx)) * 128;
#pragma unroll
      for (int rg = 0; rg < 16; ++rg) {
        int rowq = (rg & 3) + 8 * (rg >> 2) + 4 * h2;
        size_t base = (pb + w * 32 + rowq) * 128 + ql;
#pragma unroll
        for (int tb = 0; tb < 4; ++tb)
          Opart[base + tb * 32] = f2b(oacc[tb][rg]);
      }
      if (h2 == 0) {
        Mpart[pb + w * 32 + ql] = m_r;
      }
      if (ql == 0) {
#pragma unroll
        for (int rg = 0; rg < 16; ++rg) {
          int rowq = (rg & 3) + 8 * (rg >> 2) + 4 * h2;
          Lpart[pb + w * 32 + rowq] = lsum[rg];
        }
      }
    }
  };

  if (half == 0) {
    run_segment(t_l, 0, 17, 0);
  } else {
    run_segment(t_l, 17, 2 * t_l + 2, 1);
    run_segment(t_s, 0, 2 * t_s + 2, -1);
  }
}

// ---------- combine split q-tiles: O = (w0*O0 + w1*O1) / (w0*l0 + w1*l1) ----------
__global__ __launch_bounds__(256) void combine_kernel(
    const u16* __restrict__ Opart, const float* __restrict__ Mpart,
    const float* __restrict__ Lpart, u16* __restrict__ O) {
  int pidx = blockIdx.x;  // 256
  int bh = pidx >> 3, pp = pidx & 7;
  int b = bh >> 4, hh = bh & 15;
  int t_l = 15 - pp;
  int tid = threadIdx.x;
  int row = tid >> 1, colbase = (tid & 1) * 64;
  size_t pb0 = (size_t)pidx * 128 + row;
  size_t pb1 = (size_t)(256 + pidx) * 128 + row;
  float m0 = Mpart[pb0], m1 = Mpart[pb1];
  float l0 = Lpart[pb0], l1 = Lpart[pb1];
  float M = fmaxf(m0, m1);
  float w0 = exp2f(m0 - M), w1 = exp2f(m1 - M);
  float inv = 1.0f / (w0 * l0 + w1 * l1);
  size_t ob = ((size_t)(b * 2048 + t_l * 128 + row)) * 2048 + hh * 128 + colbase;
#pragma unroll
  for (int k = 0; k < 8; ++k) {
    short8 o0 = *reinterpret_cast<const short8*>(&Opart[pb0 * 128 + colbase + k * 8]);
    short8 o1 = *reinterpret_cast<const short8*>(&Opart[pb1 * 128 + colbase + k * 8]);
    short8 r;
#pragma unroll
    for (int e = 0; e < 8; ++e)
      r[e] = (short)f2b((w0 * b2f((u16)o0[e]) + w1 * b2f((u16)o1[e])) * inv);
    *reinterpret_cast<short8*>(&O[ob + k * 8]) = r;
  }
}

extern "C" void kernel_launch(void* const* d_in, const int* in_sizes, int n_in,
                              void* d_out, int out_size, void* d_ws, size_t ws_size,
                              hipStream_t stream) {
  const float* x  = (const float*)d_in[0];
  const float* wq = (const float*)d_in[1];
  const float* wk = (const float*)d_in[2];
  const float* wv = (const float*)d_in[3];
  const float* wo = (const float*)d_in[4];
  float* out = (float*)d_out;
  char* ws = (char*)d_ws;
  size_t off = 0;
  auto alloc = [&](size_t bytes) -> void* {
    void* p = ws + off;
    off = (off + bytes + 255) & ~(size_t)255;
    return p;
  };
  u16* xb   = (u16*)alloc(4096ull * 2048 * 2);  // x bf16; reused as attn output
  u16* wqb  = (u16*)alloc(2048ull * 2048 * 2);  // wqb/wkb/wvb contiguous = [3072][2048]
  u16* wkb  = (u16*)alloc(512ull * 2048 * 2);
  u16* wvb  = (u16*)alloc(512ull * 2048 * 2);
  u16* wob  = (u16*)alloc(2048ull * 2048 * 2);
  u16* qkv  = (u16*)alloc(4096ull * 3072 * 2);  // [B*S][3072] = q | k | v
  u16* kr   = (u16*)alloc(4096ull * 512 * 2);   // [B][4][S][128]
  u16* vtb  = (u16*)alloc(4096ull * 512 * 2);   // [B][4][128][S]
  float* ctab = (float*)alloc(2048ull * 64 * 4);
  float* stab = (float*)alloc(2048ull * 64 * 4);
  u16* opart  = (u16*)alloc(2ull * 256 * 128 * 128 * 2);  // split-tile partials
  float* mpart = (float*)alloc(2ull * 256 * 128 * 4);
  float* lpart = (float*)alloc(2ull * 256 * 128 * 4);
  u16* attnb = xb;  // safe: xb last read by gemm_qkv, attn runs after
  (void)in_sizes; (void)n_in; (void)out_size; (void)ws_size;

  cvt5_kernel<<<18944, 256, 0, stream>>>(x, wq, wk, wv, wo, xb, wqb, wkb, wvb, wob,
                                         ctab, stab);

  // fused q|k|v projection: [4096][2048] x [3072][2048]^T
  gemm_bt<u16, 128><<<dim3(24, 32), 256, 0, stream>>>(xb, wqb, qkv, 4096, 3072, 2048);

  kvprep_kernel<<<768, 256, 0, stream>>>(qkv, kr, vtb, ctab, stab);

  attn_kernel<<<dim3(512), 256, 0, stream>>>(qkv, kr, vtb, ctab, stab, attnb,
                                             opart, mpart, lpart);
  combine_kernel<<<dim3(256), 256, 0, stream>>>(opart, mpart, lpart, attnb);

  // out-proj: 128x64 tile -> 1024 blocks, 36KB LDS, 4 resident blocks/CU
  gemm_bt<float, 64><<<dim3(32, 32), 256, 0, stream>>>(attnb, wob, out, 4096, 2048, 2048);
}

// Round 16
// 215.322 us; speedup vs baseline: 1.0172x; 1.0172x over previous
//
#include <hip/hip_runtime.h>
#include <math.h>

typedef unsigned short u16;
typedef __attribute__((ext_vector_type(8))) short short8;
typedef __attribute__((ext_vector_type(8))) __bf16 bf16x8;
typedef __attribute__((ext_vector_type(4))) float floatx4;
typedef __attribute__((ext_vector_type(16))) float floatx16;
typedef __attribute__((ext_vector_type(4))) unsigned short u16x4;
typedef __attribute__((ext_vector_type(4))) float float4v;
typedef __attribute__((ext_vector_type(4))) unsigned int uint4v;

static __device__ __forceinline__ float b2f(u16 u) {
  unsigned int x = ((unsigned int)u) << 16;
  return __builtin_bit_cast(float, x);
}
static __device__ __forceinline__ u16 f2b(float f) {
  unsigned int x = __builtin_bit_cast(unsigned int, f);
  x += 0x7fffu + ((x >> 16) & 1u);
  return (u16)(x >> 16);
}
// pack two f32 -> two bf16 in one instruction (T12; no builtin on gfx950)
static __device__ __forceinline__ unsigned int pk2(float lo, float hi) {
  unsigned int r;
  asm("v_cvt_pk_bf16_f32 %0, %1, %2" : "=v"(r) : "v"(lo), "v"(hi));
  return r;
}
static __device__ __forceinline__ float max3f(float a, float b, float c) {
  return fmaxf(fmaxf(a, b), c);  // clang fuses to v_max3_f32
}
static __device__ __forceinline__ void gload_lds16(const void* g, void* l) {
  __builtin_amdgcn_global_load_lds(
      (const __attribute__((address_space(1))) unsigned int*)g,
      (__attribute__((address_space(3))) unsigned int*)l, 16, 0, 0);
}

// ---------- fused fp32 -> bf16 convert for all 5 inputs + RoPE tables ----------
__global__ __launch_bounds__(256) void cvt5_kernel(
    const float* __restrict__ x, const float* __restrict__ wq,
    const float* __restrict__ wk, const float* __restrict__ wv,
    const float* __restrict__ wo, u16* __restrict__ xb, u16* __restrict__ wqb,
    u16* __restrict__ wkb, u16* __restrict__ wvb, u16* __restrict__ wob,
    float* __restrict__ ct, float* __restrict__ st) {
  int bid = blockIdx.x;
  if (bid >= 18432) {  // RoPE cos/sin tables: [S=2048][64] fp32
    int idx = (bid - 18432) * 256 + threadIdx.x;
    int s = idx >> 6, j = idx & 63;
    float inv = powf(10000.0f, -(float)j * (1.0f / 64.0f));
    float ang = (float)s * inv;
    ct[idx] = cosf(ang);
    st[idx] = sinf(ang);
    return;
  }
  const float* in;
  u16* out;
  int i0;
  if (bid < 8192) { in = x; out = xb; i0 = bid; }
  else if (bid < 12288) { in = wq; out = wqb; i0 = bid - 8192; }
  else if (bid < 13312) { in = wk; out = wkb; i0 = bid - 12288; }
  else if (bid < 14336) { in = wv; out = wvb; i0 = bid - 13312; }
  else { in = wo; out = wob; i0 = bid - 14336; }
  int i = i0 * 256 + threadIdx.x;
  float4v v = reinterpret_cast<const float4v*>(in)[i];
  u16x4 o;
  o[0] = f2b(v[0]); o[1] = f2b(v[1]); o[2] = f2b(v[2]); o[3] = f2b(v[3]);
  reinterpret_cast<u16x4*>(out)[i] = o;
}

// ---------- fused K-RoPE + V-transpose (one launch) ----------
__global__ __launch_bounds__(256) void kvprep_kernel(const u16* __restrict__ in,
                                                     u16* __restrict__ kr,
                                                     u16* __restrict__ vtb,
                                                     const float* __restrict__ ct,
                                                     const float* __restrict__ st) {
  __shared__ u16 t[128][66];
  if (blockIdx.x < 512) {
    int idx = blockIdx.x * 256 + threadIdx.x;  // B*S*4*8 = 131072
    int jc = idx & 7;
    int rest = idx >> 3;
    int h = rest & 3;
    int bs = rest >> 2;
    int s = bs & 2047;
    int b = bs >> 11;
    int j0 = jc * 8;
    size_t inoff = (size_t)bs * 3072 + 2048 + h * 128 + j0;
    short8 lo = *reinterpret_cast<const short8*>(&in[inoff]);
    short8 hi = *reinterpret_cast<const short8*>(&in[inoff + 64]);
    short8 o0, o1;
#pragma unroll
    for (int e = 0; e < 8; ++e) {
      float c = ct[s * 64 + j0 + e], sn = st[s * 64 + j0 + e];
      float t1 = b2f((u16)lo[e]);
      float t2 = b2f((u16)hi[e]);
      o0[e] = (short)f2b(t1 * c - t2 * sn);
      o1[e] = (short)f2b(t2 * c + t1 * sn);
    }
    size_t ooff = ((size_t)(b * 4 + h) * 2048 + s) * 128 + j0;
    *reinterpret_cast<short8*>(&kr[ooff]) = o0;
    *reinterpret_cast<short8*>(&kr[ooff + 64]) = o1;
  } else {
    int vb = blockIdx.x - 512;  // 256 blocks
    int s0 = (vb & 31) * 64;
    int by = vb >> 5;
    int b = by >> 2, kv = by & 3;
    int tid = threadIdx.x;
#pragma unroll
    for (int it = 0; it < 32; ++it) {
      int idx = it * 256 + tid;
      int sl = idx >> 7, d = idx & 127;
      t[d][sl] = in[(size_t)(b * 2048 + s0 + sl) * 3072 + 2560 + kv * 128 + d];
    }
    __syncthreads();
#pragma unroll
    for (int it = 0; it < 32; ++it) {
      int idx = it * 256 + tid;
      int d = idx >> 6, sl = idx & 63;
      vtb[(size_t)((b * 4 + kv) * 128 + d) * 2048 + s0 + sl] = t[d][sl];
    }
  }
}

// ---------- bf16 GEMM: triple-buffered LDS + counted vmcnt + raw s_barrier ----------
// C[M][N] = A[M][K] * B[N][K]^T, 128x128 tile, BK=32, 4 waves.
// Wave (wr, wc) owns rows wr*64..+64, cols wc*64..+64. 4 loads/stage, vmcnt(4);
// 48KB LDS, 3 blocks/CU. BN=64 variant measured +3us total (r15): halving BN
// halves MFMA-per-load and doubles A re-fetch -> 128x128 is the better point.
static __device__ __forceinline__ void store_out(u16* p, float v) { *p = f2b(v); }
static __device__ __forceinline__ void store_out(float* p, float v) { *p = v; }

template <typename OutT>
__global__ __launch_bounds__(256) void gemm_bt(const u16* __restrict__ A,
                                               const u16* __restrict__ B,
                                               OutT* __restrict__ C, int M, int N, int K) {
  __shared__ __align__(16) u16 Al[3][128 * 32];
  __shared__ __align__(16) u16 Bl[3][128 * 32];
  const int tid = threadIdx.x;
  const int lane = tid & 63;
  const int w = tid >> 6;
  const int wr = w >> 1, wc = w & 1;
  const int lr = lane & 15, lg = lane >> 4;
  const int brow = blockIdx.y, bcol = blockIdx.x;
  const int r0 = lane >> 2, kp = lane & 3;
  const u16* Ag = A + (size_t)(brow * 128) * K;
  const u16* Bg = B + (size_t)(bcol * 128) * K;
  floatx4 acc[4][4] = {};
  const int NT = K >> 5;

  auto stage = [&](int buf, int t) {
#pragma unroll
    for (int j = 0; j < 2; ++j) {
      int c = w * 2 + j;
      int row = c * 16 + r0;
      gload_lds16(Ag + (size_t)row * K + t * 32 + kp * 8, &Al[buf][c * 512]);
      gload_lds16(Bg + (size_t)row * K + t * 32 + kp * 8, &Bl[buf][c * 512]);
    }
  };

  stage(0, 0);
  stage(1, 1);
  asm volatile("s_waitcnt vmcnt(4)\n\ts_barrier" ::: "memory");

  int cur = 0, nxt = 2;  // nxt = (cur+2)%3
  for (int t = 0; t < NT; ++t) {
    if (t + 2 < NT) stage(nxt, t + 2);
    bf16x8 af[4], bfr[4];
#pragma unroll
    for (int m = 0; m < 4; ++m)
      af[m] = *reinterpret_cast<const bf16x8*>(&Al[cur][(wr * 64 + m * 16 + lr) * 32 + lg * 8]);
#pragma unroll
    for (int n = 0; n < 4; ++n)
      bfr[n] = *reinterpret_cast<const bf16x8*>(&Bl[cur][(wc * 64 + n * 16 + lr) * 32 + lg * 8]);
    __builtin_amdgcn_s_setprio(1);
#pragma unroll
    for (int m = 0; m < 4; ++m)
#pragma unroll
      for (int n = 0; n < 4; ++n)
        acc[m][n] = __builtin_amdgcn_mfma_f32_16x16x32_bf16(af[m], bfr[n], acc[m][n], 0, 0, 0);
    __builtin_amdgcn_s_setprio(0);
    if (t + 2 < NT) {
      asm volatile("s_waitcnt vmcnt(4)\n\ts_barrier" ::: "memory");
    } else if (t + 1 < NT) {
      asm volatile("s_waitcnt vmcnt(0)\n\ts_barrier" ::: "memory");
    }
    cur = (cur == 2) ? 0 : cur + 1;
    nxt = (nxt == 2) ? 0 : nxt + 1;
  }
#pragma unroll
  for (int m = 0; m < 4; ++m) {
    int row = brow * 128 + wr * 64 + m * 16 + lg * 4;
#pragma unroll
    for (int n = 0; n < 4; ++n) {
      int col = bcol * 128 + wc * 64 + n * 16 + lr;
#pragma unroll
      for (int i = 0; i < 4; ++i) store_out(&C[(size_t)(row + i) * N + col], acc[m][n][i]);
    }
  }
}

// ---------- causal GQA flash attention (r11 known-good config) ----------
// Uniform 17-tile blocks + combine; double-buffered K/V (64KB, 2 blocks/CU);
// scale folded into Q, ones-trick row-sums, max3 tree, defer-max, cvt_pk+permlane.
// Register floor ~208 total/lane -> 2 blocks/CU hard floor (r10: 4/CU spills).
// Deferred-PV pipeline (r12) measured -3%: per-iter barrier phase-aligns waves,
// so intra-wave ILP restructuring is null. Latency-bound local optimum.
__global__ __launch_bounds__(256, 2) void attn_kernel(
    const u16* __restrict__ QKV, const u16* __restrict__ K,
    const u16* __restrict__ V, const float* __restrict__ ct,
    const float* __restrict__ st, u16* __restrict__ O, u16* __restrict__ Opart,
    float* __restrict__ Mpart, float* __restrict__ Lpart) {
  __shared__ __align__(16) u16 Kl[2][64 * 128];  // [64 k][128 d], slot-XOR swizzled
  __shared__ __align__(16) u16 Vl[2][128 * 64];  // [128 d][64 k], slot-XOR swizzled
  const int tid = threadIdx.x, lane = tid & 63, w = tid >> 6;
  const int ql = lane & 31, h2 = lane >> 5;
  const int idx = blockIdx.x;  // 512 blocks
  const int bh = idx & 31, pp = (idx >> 5) & 7, half = idx >> 8;
  const int b = bh >> 4, hh = bh & 15, kv = hh >> 2;
  const int t_l = 15 - pp, t_s = pp;
  const int pidx = bh * 8 + pp;
  const u16* Kp = K + (size_t)(b * 4 + kv) * 2048 * 128;
  const u16* Vp = V + (size_t)(b * 4 + kv) * 128 * 2048;
  const float cl = 0.08838834764831845f * 1.44269504088896f;  // 1/sqrt(128)*log2e
  const uint4v ones_u = {0x3F803F80u, 0x3F803F80u, 0x3F803F80u, 0x3F803F80u};
  const bf16x8 ones = __builtin_bit_cast(bf16x8, ones_u);

  auto stage = [&](int buf, int kb) {
#pragma unroll
    for (int j = 0; j < 4; ++j) {
      int slot = j * 256 + tid;  // 16B slots
      int row = slot >> 4, d16 = slot & 15;
      gload_lds16(Kp + (size_t)(kb * 64 + row) * 128 + (d16 ^ (row & 15)) * 8,
                  &Kl[buf][(j * 256 + w * 64) * 8]);
      int d = slot >> 3, k8 = slot & 7;
      gload_lds16(Vp + (size_t)d * 2048 + kb * 64 + (k8 ^ (d & 7)) * 8,
                  &Vl[buf][(j * 256 + w * 64) * 8]);
    }
  };

  // run one q-tile over kv tiles [kvs, kve). part: -1 = final write, 0/1 = partial.
  auto run_segment = [&](int t, int kvs, int kve, int part) {
    const int q0w = t * 128 + w * 32;
    const int qg = q0w + ql;
    // Q load + fused RoPE (pre-scaled by cl) -> B-operand frags
    bf16x8 qa[8];
    {
      const u16* qp = QKV + ((size_t)(b * 2048 + qg)) * 3072 + hh * 128;
      short8 rr[8];
#pragma unroll
      for (int dk = 0; dk < 8; ++dk)
        rr[dk] = *reinterpret_cast<const short8*>(qp + dk * 16 + h2 * 8);
      const float* cb = ct + (size_t)qg * 64;
      const float* sb = st + (size_t)qg * 64;
#pragma unroll
      for (int dk = 0; dk < 4; ++dk) {
        short8 olo, ohi;
#pragma unroll
        for (int e = 0; e < 8; ++e) {
          int j = dk * 16 + h2 * 8 + e;  // 0..63
          float c = cb[j] * cl, sn = sb[j] * cl;
          float t1 = b2f((u16)rr[dk][e]);
          float t2 = b2f((u16)rr[dk + 4][e]);
          olo[e] = (short)f2b(t1 * c - t2 * sn);
          ohi[e] = (short)f2b(t2 * c + t1 * sn);
        }
        qa[dk] = __builtin_bit_cast(bf16x8, olo);
        qa[dk + 4] = __builtin_bit_cast(bf16x8, ohi);
      }
    }
    float m_r = -1e30f;
    floatx16 oacc[4] = {};
    floatx16 lsum = {};
    stage(0, kvs);
    __syncthreads();
    int cur = 0;
    for (int kb = kvs; kb < kve; ++kb) {
      if (kb + 1 < kve) stage(cur ^ 1, kb + 1);
      if (kb * 64 <= q0w + 31) {
        const u16* Klc = Kl[cur];
        const u16* Vlc = Vl[cur];
        floatx16 sT0 = {}, sT1 = {};
        __builtin_amdgcn_s_setprio(1);
#pragma unroll
        for (int dk = 0; dk < 8; ++dk) {
          int row0 = ql, row1 = 32 + ql;
          bf16x8 ak0 = *reinterpret_cast<const bf16x8*>(
              &Klc[row0 * 128 + (((dk * 2 + h2) ^ (row0 & 15))) * 8]);
          bf16x8 ak1 = *reinterpret_cast<const bf16x8*>(
              &Klc[row1 * 128 + (((dk * 2 + h2) ^ (row1 & 15))) * 8]);
          sT0 = __builtin_amdgcn_mfma_f32_32x32x16_bf16(ak0, qa[dk], sT0, 0, 0, 0);
          sT1 = __builtin_amdgcn_mfma_f32_32x32x16_bf16(ak1, qa[dk], sT1, 0, 0, 0);
        }
        __builtin_amdgcn_s_setprio(0);
        float x[32];
        const bool domask = (kb * 64 + 63 > q0w);
#pragma unroll
        for (int rg = 0; rg < 16; ++rg) {
          int kloc0 = (rg & 3) + 8 * (rg >> 2) + 4 * h2;
          float v0 = sT0[rg];
          float v1 = sT1[rg];
          if (domask) {
            if (kb * 64 + kloc0 > qg) v0 = -1e30f;
            if (kb * 64 + 32 + kloc0 > qg) v1 = -1e30f;
          }
          x[rg] = v0;
          x[16 + rg] = v1;
        }
        // max tree: 16 pairwise + max3 levels (24 ops)
        float mx[16];
#pragma unroll
        for (int i = 0; i < 16; ++i) mx[i] = fmaxf(x[i], x[i + 16]);
        float y0 = max3f(mx[0], mx[1], mx[2]);
        float y1 = max3f(mx[3], mx[4], mx[5]);
        float y2 = max3f(mx[6], mx[7], mx[8]);
        float y3 = max3f(mx[9], mx[10], mx[11]);
        float y4 = max3f(mx[12], mx[13], mx[14]);
        float tmax = fmaxf(max3f(y0, y1, y2), max3f(y3, y4, mx[15]));
        tmax = fmaxf(tmax, __shfl_xor(tmax, 32));
        if (!__all(tmax - m_r <= 11.0f)) {  // defer-max, log2 units
          float mn = fmaxf(m_r, tmax);
          float al = exp2f(m_r - mn);
          m_r = mn;
#pragma unroll
          for (int rg = 0; rg < 16; ++rg) {
            int rowq = (rg & 3) + 8 * (rg >> 2) + 4 * h2;
            float arow = __shfl(al, rowq);
            oacc[0][rg] *= arow; oacc[1][rg] *= arow;
            oacc[2][rg] *= arow; oacc[3][rg] *= arow;
            lsum[rg] *= arow;
          }
        }
        float p[32];
#pragma unroll
        for (int i = 0; i < 32; ++i) p[i] = exp2f(x[i] - m_r);
        bf16x8 pa[4];
#pragma unroll
        for (int ka = 0; ka < 2; ++ka) {
          const int o = ka * 16;
          unsigned int x0 = pk2(p[o + 0], p[o + 1]);
          unsigned int x1 = pk2(p[o + 2], p[o + 3]);
          unsigned int y0u = pk2(p[o + 4], p[o + 5]);
          unsigned int y1u = pk2(p[o + 6], p[o + 7]);
          asm volatile("v_permlane32_swap_b32 %0, %1" : "+v"(x0), "+v"(y0u));
          asm volatile("v_permlane32_swap_b32 %0, %1" : "+v"(x1), "+v"(y1u));
          uint4v f0 = {x0, x1, y0u, y1u};
          pa[ka * 2] = __builtin_bit_cast(bf16x8, f0);
          unsigned int z0 = pk2(p[o + 8], p[o + 9]);
          unsigned int z1 = pk2(p[o + 10], p[o + 11]);
          unsigned int u0 = pk2(p[o + 12], p[o + 13]);
          unsigned int u1 = pk2(p[o + 14], p[o + 15]);
          asm volatile("v_permlane32_swap_b32 %0, %1" : "+v"(z0), "+v"(u0));
          asm volatile("v_permlane32_swap_b32 %0, %1" : "+v"(z1), "+v"(u1));
          uint4v f1 = {z0, z1, u0, u1};
          pa[ka * 2 + 1] = __builtin_bit_cast(bf16x8, f1);
        }
        __builtin_amdgcn_s_setprio(1);
#pragma unroll
        for (int tb = 0; tb < 4; ++tb) {
          int d = tb * 32 + ql;
#pragma unroll
          for (int ks = 0; ks < 4; ++ks) {
            bf16x8 bv = *reinterpret_cast<const bf16x8*>(
                &Vlc[d * 64 + (((ks * 2 + h2) ^ (d & 7))) * 8]);
            oacc[tb] = __builtin_amdgcn_mfma_f32_32x32x16_bf16(pa[ks], bv, oacc[tb], 0, 0, 0);
          }
        }
        // l row-sums via ones-trick: lsum[rg] = sum_k P[rowq][k] for every col
#pragma unroll
        for (int ks = 0; ks < 4; ++ks)
          lsum = __builtin_amdgcn_mfma_f32_32x32x16_bf16(pa[ks], ones, lsum, 0, 0, 0);
        __builtin_amdgcn_s_setprio(0);
      }
      __syncthreads();
      cur ^= 1;
    }
    if (part < 0) {
#pragma unroll
      for (int rg = 0; rg < 16; ++rg) {
        int rowq = (rg & 3) + 8 * (rg >> 2) + 4 * h2;
        float inv = 1.0f / lsum[rg];
        int qrow = t * 128 + w * 32 + rowq;
        size_t base = ((size_t)(b * 2048 + qrow)) * 2048 + hh * 128 + ql;
#pragma unroll
        for (int tb = 0; tb < 4; ++tb)
          O[base + tb * 32] = f2b(oacc[tb][rg] * inv);
      }
    } else {
      // unnormalized partial + (m, l) per q-row
      size_t pb = ((size_t)(part * 256 + pidx)) * 128;
#pragma unroll
      for (int rg = 0; rg < 16; ++rg) {
        int rowq = (rg & 3) + 8 * (rg >> 2) + 4 * h2;
        size_t base = (pb + w * 32 + rowq) * 128 + ql;
#pragma unroll
        for (int tb = 0; tb < 4; ++tb)
          Opart[base + tb * 32] = f2b(oacc[tb][rg]);
      }
      if (h2 == 0) {
        Mpart[pb + w * 32 + ql] = m_r;
      }
      if (ql == 0) {
#pragma unroll
        for (int rg = 0; rg < 16; ++rg) {
          int rowq = (rg & 3) + 8 * (rg >> 2) + 4 * h2;
          Lpart[pb + w * 32 + rowq] = lsum[rg];
        }
      }
    }
  };

  if (half == 0) {
    run_segment(t_l, 0, 17, 0);
  } else {
    run_segment(t_l, 17, 2 * t_l + 2, 1);
    run_segment(t_s, 0, 2 * t_s + 2, -1);
  }
}

// ---------- combine split q-tiles: O = (w0*O0 + w1*O1) / (w0*l0 + w1*l1) ----------
__global__ __launch_bounds__(256) void combine_kernel(
    const u16* __restrict__ Opart, const float* __restrict__ Mpart,
    const float* __restrict__ Lpart, u16* __restrict__ O) {
  int pidx = blockIdx.x;  // 256
  int bh = pidx >> 3, pp = pidx & 7;
  int b = bh >> 4, hh = bh & 15;
  int t_l = 15 - pp;
  int tid = threadIdx.x;
  int row = tid >> 1, colbase = (tid & 1) * 64;
  size_t pb0 = (size_t)pidx * 128 + row;
  size_t pb1 = (size_t)(256 + pidx) * 128 + row;
  float m0 = Mpart[pb0], m1 = Mpart[pb1];
  float l0 = Lpart[pb0], l1 = Lpart[pb1];
  float M = fmaxf(m0, m1);
  float w0 = exp2f(m0 - M), w1 = exp2f(m1 - M);
  float inv = 1.0f / (w0 * l0 + w1 * l1);
  size_t ob = ((size_t)(b * 2048 + t_l * 128 + row)) * 2048 + hh * 128 + colbase;
#pragma unroll
  for (int k = 0; k < 8; ++k) {
    short8 o0 = *reinterpret_cast<const short8*>(&Opart[pb0 * 128 + colbase + k * 8]);
    short8 o1 = *reinterpret_cast<const short8*>(&Opart[pb1 * 128 + colbase + k * 8]);
    short8 r;
#pragma unroll
    for (int e = 0; e < 8; ++e)
      r[e] = (short)f2b((w0 * b2f((u16)o0[e]) + w1 * b2f((u16)o1[e])) * inv);
    *reinterpret_cast<short8*>(&O[ob + k * 8]) = r;
  }
}

extern "C" void kernel_launch(void* const* d_in, const int* in_sizes, int n_in,
                              void* d_out, int out_size, void* d_ws, size_t ws_size,
                              hipStream_t stream) {
  const float* x  = (const float*)d_in[0];
  const float* wq = (const float*)d_in[1];
  const float* wk = (const float*)d_in[2];
  const float* wv = (const float*)d_in[3];
  const float* wo = (const float*)d_in[4];
  float* out = (float*)d_out;
  char* ws = (char*)d_ws;
  size_t off = 0;
  auto alloc = [&](size_t bytes) -> void* {
    void* p = ws + off;
    off = (off + bytes + 255) & ~(size_t)255;
    return p;
  };
  u16* xb   = (u16*)alloc(4096ull * 2048 * 2);  // x bf16; reused as attn output
  u16* wqb  = (u16*)alloc(2048ull * 2048 * 2);  // wqb/wkb/wvb contiguous = [3072][2048]
  u16* wkb  = (u16*)alloc(512ull * 2048 * 2);
  u16* wvb  = (u16*)alloc(512ull * 2048 * 2);
  u16* wob  = (u16*)alloc(2048ull * 2048 * 2);
  u16* qkv  = (u16*)alloc(4096ull * 3072 * 2);  // [B*S][3072] = q | k | v
  u16* kr   = (u16*)alloc(4096ull * 512 * 2);   // [B][4][S][128]
  u16* vtb  = (u16*)alloc(4096ull * 512 * 2);   // [B][4][128][S]
  float* ctab = (float*)alloc(2048ull * 64 * 4);
  float* stab = (float*)alloc(2048ull * 64 * 4);
  u16* opart  = (u16*)alloc(2ull * 256 * 128 * 128 * 2);  // split-tile partials
  float* mpart = (float*)alloc(2ull * 256 * 128 * 4);
  float* lpart = (float*)alloc(2ull * 256 * 128 * 4);
  u16* attnb = xb;  // safe: xb last read by gemm_qkv, attn runs after
  (void)in_sizes; (void)n_in; (void)out_size; (void)ws_size;

  cvt5_kernel<<<18944, 256, 0, stream>>>(x, wq, wk, wv, wo, xb, wqb, wkb, wvb, wob,
                                         ctab, stab);

  // fused q|k|v projection: [4096][2048] x [3072][2048]^T
  gemm_bt<u16><<<dim3(24, 32), 256, 0, stream>>>(xb, wqb, qkv, 4096, 3072, 2048);

  kvprep_kernel<<<768, 256, 0, stream>>>(qkv, kr, vtb, ctab, stab);

  attn_kernel<<<dim3(512), 256, 0, stream>>>(qkv, kr, vtb, ctab, stab, attnb,
                                             opart, mpart, lpart);
  combine_kernel<<<dim3(256), 256, 0, stream>>>(opart, mpart, lpart, attnb);

  gemm_bt<float><<<dim3(16, 32), 256, 0, stream>>>(attnb, wob, out, 4096, 2048, 2048);
}